// Round 12
// baseline (27.726 us; speedup 1.0000x reference)
//
#include <hip/hip_runtime.h>
#include <math.h>

namespace {

constexpr int kNB    = 16;
constexpr int kFrame = 2048;
constexpr int kSub   = 8;    // 4 streams of 8 samples per lane (2 packed regs)

typedef float f32x2 __attribute__((ext_vector_type(2)));

__device__ inline f32x2 pk_fma(f32x2 a, f32x2 b, f32x2 c) {
    f32x2 d;
    asm("v_pk_fma_f32 %0, %1, %2, %3" : "=v"(d) : "v"(a), "v"(b), "v"(c));
    return d;
}
__device__ inline f32x2 pk_mul(f32x2 a, f32x2 b) {
    f32x2 d;
    asm("v_pk_mul_f32 %0, %1, %2" : "=v"(d) : "v"(a), "v"(b));
    return d;
}
__device__ inline f32x2 pk_add(f32x2 a, f32x2 b) {
    f32x2 d;
    asm("v_pk_add_f32 %0, %1, %2" : "=v"(d) : "v"(a), "v"(b));
    return d;
}

// DPP move with bound_ctrl=1 (out-of-range -> 0)
template <int CTRL>
__device__ inline float dpp_f(float v) {
    return __int_as_float(
        __builtin_amdgcn_update_dpp(0, __float_as_int(v), CTRL, 0xF, 0xF, true));
}

// one uniform-matrix Kogge-Stone level via row_shr DPP (intra-row-16)
template <int CTRL>
__device__ inline void ks_level(float& v0, float& v1, const float4 M, const float na1) {
    const float t0 = dpp_f<CTRL>(v0);
    const float t1 = dpp_f<CTRL>(v1);
    const float w  = fmaf(na1, t0, t1);
    v0 = fmaf(M.x, w,  fmaf(M.y, t0, v0));
    v1 = fmaf(M.z, t0, fmaf(M.y, t1, v1));
}

// Block = 64 threads = 1 wave = 1 channel. Lane owns 32 consecutive samples as
// 4 independent streams of 8 (2 packed regs -> ILP 2 in the serial phases).
// Cross-lane scan is 100% DPP.
__global__ __launch_bounds__(64)
void biquad_chain_kernel(const float* __restrict__ audio,
                         const float* __restrict__ params,
                         float* __restrict__ out)
{
    // sK[b][0] = (b0, b1, b2, na1); sK[b][1] = (na2, al16, be16, ga16)  [A^16]
    __shared__ float4 sK[kNB][2];
    // powT[b][i] = (al, be, ga, 0) for M^(i+1), M = A^32, i = 0..31;
    // col 32 = (al8, be8, ga8, 0)  [A^8]
    __shared__ float4 powT[kNB][33];

    const int lane = threadIdx.x & 63;
    const int ch   = blockIdx.x;      // 0..2047
    const int bb   = ch >> 7;
    const int ff   = ch & 127;

    const float* pb = params + (size_t)bb * (50 * 128) + ff;

    // ---- hoisted audio load (HBM latency hides under the preamble) ----
    // P[t] = (x[t], x[t+8]); Q[t] = (x[t+16], x[t+24]), t = 0..7
    f32x2 P[kSub], Q[kSub];
    {
        const float4* ap = reinterpret_cast<const float4*>(
            audio + (size_t)ch * kFrame + lane * 32);
        const float4 f0 = ap[0], f1 = ap[1], f2 = ap[2], f3 = ap[3];
        const float4 f4 = ap[4], f5 = ap[5], f6 = ap[6], f7 = ap[7];
        P[0] = f32x2{f0.x, f2.x}; P[1] = f32x2{f0.y, f2.y};
        P[2] = f32x2{f0.z, f2.z}; P[3] = f32x2{f0.w, f2.w};
        P[4] = f32x2{f1.x, f3.x}; P[5] = f32x2{f1.y, f3.y};
        P[6] = f32x2{f1.z, f3.z}; P[7] = f32x2{f1.w, f3.w};
        Q[0] = f32x2{f4.x, f6.x}; Q[1] = f32x2{f4.y, f6.y};
        Q[2] = f32x2{f4.z, f6.z}; Q[3] = f32x2{f4.w, f6.w};
        Q[4] = f32x2{f5.x, f7.x}; Q[5] = f32x2{f5.y, f7.y};
        Q[6] = f32x2{f5.z, f7.z}; Q[7] = f32x2{f5.w, f7.w};
    }

    // ---- preamble: all 64 lanes; lane -> (band = lane&15, part = lane>>4) ----
    {
        const int band = lane & 15;
        const int part = lane >> 4;
        const float fn = pb[(band * 3 + 0) * 128];
        const float gn = pb[(band * 3 + 1) * 128];
        const float qn = pb[(band * 3 + 2) * 128];

        const bool isHP = (band == 0), isLP = (band == kNB - 1);
        const bool isShelf = (band == 1) || (band == kNB - 2);
        const float flo = isHP ? 2.995732274f
                        : isLP ? 8.517193191f
                        : isShelf ? 3.912023005f
                        : 4.605170186f;
        const float fsp = isHP ? 3.218875825f
                        : isLP ? 1.386294361f
                        : isShelf ? 5.768320996f
                        : 5.010635294f;

        // f32 transcendental block (exp via HW; sin/cos via cancellation-safe
        // half-angle Taylor: ver = 1-cos(w0) = 2*sh^2, sin(w0) = 2*sh*ch)
        const float Q_  = __expf(fmaf(qn, 3.465735903f, -0.6931471806f));
        const float fc = __expf(fmaf(fn, fsp, flo));
        const float hw = fc * 3.272492349e-5f;        // pi/96000: w0/2
        const float x2 = hw * hw;
        const float sh = hw * fmaf(x2, fmaf(x2, fmaf(x2, -1.984126984e-4f,
                                   8.333333333e-3f), -0.1666666667f), 1.0f);
        const float chh = sqrtf(fmaf(-sh, sh, 1.0f));
        const float sw  = 2.0f * sh * chh;            // sin(w0)
        const float ver = 2.0f * sh * sh;             // 1 - cos(w0)
        const float alq = sw / (Q_ + Q_);
        const float gdb = (isHP || isLP) ? 0.f : fmaf(gn, 48.f, -24.f);
        const float A   = __expf(gdb * 0.05756462732f);   // ln10/40
        const float sA  = sqrtf(A);
        const float ge  = isHP ? fmaf(pb[48 * 128], 60.f, -60.f) * 0.1151292546f
                        : isLP ? fmaf(pb[49 * 128], 60.f, -60.f) * 0.1151292546f
                        : 0.f;
        const float gm  = __expf(ge);

        float b0, b1, b2, a0, a1, a2;
        if (isHP) {
            b0 = 1.0f - 0.5f * ver; b1 = ver - 2.0f; b2 = b0;
            a0 = 1.0f + alq; a1 = 2.0f * ver - 2.0f; a2 = 1.0f - alq;
        } else if (isLP) {
            b0 = 0.5f * ver; b1 = ver; b2 = b0;
            a0 = 1.0f + alq; a1 = 2.0f * ver - 2.0f; a2 = 1.0f - alq;
        } else if (band == 1) {                // low shelf (ver form)
            const float t = 2.0f * sA * alq;
            const float u = (A - 1.0f) * ver;
            const float w = (A + 1.0f) * ver;
            b0 = A * (2.0f + u + t);
            b1 = A * (2.0f * w - 4.0f);
            b2 = A * (2.0f + u - t);
            a0 = 2.0f * A - u + t;
            a1 = 2.0f * w - 4.0f * A;
            a2 = 2.0f * A - u - t;
        } else if (band == kNB - 2) {          // high shelf (ver form)
            const float t = 2.0f * sA * alq;
            const float u = (A - 1.0f) * ver;
            const float w = (A + 1.0f) * ver;
            b0 = A * (2.0f * A - u + t);
            b1 = -2.0f * A * (2.0f * A - w);
            b2 = A * (2.0f * A - u - t);
            a0 = 2.0f + u + t;
            a1 = 2.0f * w - 4.0f;
            a2 = 2.0f + u - t;
        } else {                               // peaking
            const float alA  = alq * A;
            const float aloA = alq / A;
            b0 = 1.0f + alA; b1 = 2.0f * ver - 2.0f; b2 = 1.0f - alA;
            a0 = 1.0f + aloA; a1 = b1; a2 = 1.0f - aloA;
        }
        const float inv  = 1.0f / a0;
        const float binv = inv * gm;
        b0 *= binv; b1 *= binv; b2 *= binv;
        a1 *= inv; a2 *= inv;

        // f64 CH doubling chain on the f32-rounded (a1, a2)
        const double a1d = (double)a1, a2d = (double)a2;
        double alc = 1.0, bec = 0.0;
        double al8 = 0, be8 = 0;
        double al16 = 0, be16 = 0, al32 = 0, be32 = 0;
        double al256 = 0, be256 = 0, al512 = 0, be512 = 0;
        #pragma unroll
        for (int k = 1; k <= 9; ++k) {
            const double a_ = alc, b_ = bec;
            alc = a_ * (2.0 * b_ - a1d * a_);
            bec = b_ * b_ - a2d * (a_ * a_);
            if (k == 3) { al8  = alc; be8  = bec; }
            if (k == 4) { al16 = alc; be16 = bec; }
            if (k == 5) { al32 = alc; be32 = bec; }
            if (k == 8) { al256 = alc; be256 = bec; }
            if (k == 9) { al512 = alc; be512 = bec; }
        }
        auto cmp = [&](double alx, double bex, double aly, double bey,
                       double& alo, double& beo) {
            const double p = alx * aly;
            alo = alx * bey + bex * aly - a1d * p;
            beo = bex * bey - a2d * p;
        };

        // part start: S = M^(8*part+1), M = A^32
        double Sa, Sb;
        if (part == 0)      { Sa = al32; Sb = be32; }
        else if (part == 1) { cmp(al256, be256, al32, be32, Sa, Sb); }
        else if (part == 2) { cmp(al512, be512, al32, be32, Sa, Sb); }
        else { double ta, tb; cmp(al512, be512, al256, be256, ta, tb);
               cmp(ta, tb, al32, be32, Sa, Sb); }

        #pragma unroll
        for (int j = 0; j < 8; ++j) {
            powT[band][8 * part + j] =
                float4{(float)Sa, (float)Sb, (float)(-a2d * Sa), 0.f};
            double na, nb;
            cmp(Sa, Sb, al32, be32, na, nb);
            Sa = na; Sb = nb;
        }
        if (part == 0) {
            sK[band][0] = float4{b0, b1, b2, -a1};
            sK[band][1] = float4{-a2, (float)al16, (float)be16,
                                 (float)(-a2d * al16)};
            powT[band][32] = float4{(float)al8, (float)be8,
                                    (float)(-a2d * al8), 0.f};
        }
    }
    __syncthreads();

    // ---- cascade ----
    for (int band = 0; band < kNB; ++band) {
        const float4 k0 = sK[band][0];
        const float4 k1 = sK[band][1];
        const float4 K8 = powT[band][32];
        const float4 P1c = powT[band][0];
        const float4 P2c = powT[band][1];
        const float4 P4c = powT[band][3];
        const float4 P8c = powT[band][7];
        const float4 Pme = powT[band][lane & 15];   // M^((lane&15)+1)
        const float4 Qme = powT[band][lane & 31];   // M^((lane&31)+1)

        const float b0 = k0.x, b1 = k0.y, b2 = k0.z, na1 = k0.w;
        const float na2 = k1.x, al16 = k1.y, be16 = k1.z, ga16 = k1.w;
        const float al8 = K8.x, be8 = K8.y, ga8 = K8.z;
        const f32x2 b0p  = {b0, b0},  b1p = {b1, b1}, b2p = {b2, b2};
        const f32x2 na1p = {na1, na1}, na2p = {na2, na2};

        // phase 1: four independent zero-state 8-sample streams (2 pk chains)
        f32x2 s1P = {0.f, 0.f}, s2P = {0.f, 0.f};
        f32x2 s1Q = {0.f, 0.f}, s2Q = {0.f, 0.f};
        #pragma unroll
        for (int t = 0; t < kSub; ++t) {
            const f32x2 xp = P[t];
            const f32x2 xq = Q[t];
            const f32x2 yp = pk_fma(b0p, xp, s1P);
            const f32x2 yq = pk_fma(b0p, xq, s1Q);
            const f32x2 tp = pk_fma(b1p, xp, s2P);
            const f32x2 tq = pk_fma(b1p, xq, s2Q);
            s2P = pk_fma(na2p, yp, pk_mul(b2p, xp));
            s2Q = pk_fma(na2p, yq, pk_mul(b2p, xq));
            s1P = pk_fma(na1p, yp, tp);
            s1Q = pk_fma(na1p, yq, tq);
            P[t] = yp;
            Q[t] = yq;
        }

        // fold 4 stream deltas -> 32-sample chunk delta
        // d01 = A^8*dS0 + dS1 ; d23 = A^8*dS2 + dS3 ; d = A^16*d01 + d23
        const float wp = fmaf(na1, s1P.x, s2P.x);
        const float d01_0 = fmaf(al8, wp, fmaf(be8, s1P.x, s1P.y));
        const float d01_1 = fmaf(ga8, s1P.x, fmaf(be8, s2P.x, s2P.y));
        const float wq = fmaf(na1, s1Q.x, s2Q.x);
        const float d23_0 = fmaf(al8, wq, fmaf(be8, s1Q.x, s1Q.y));
        const float d23_1 = fmaf(ga8, s1Q.x, fmaf(be8, s2Q.x, s2Q.y));
        const float wd = fmaf(na1, d01_0, d01_1);
        const float d0 = fmaf(al16, wd, fmaf(be16, d01_0, d23_0));
        const float d1 = fmaf(ga16, d01_0, fmaf(be16, d01_1, d23_1));

        // ---- DS-free exclusive affine scan over 64 chunks, M = A^32 ----
        float v0 = dpp_f<0x138>(d0);     // wave_shr:1 (lane 0 -> 0)
        float v1 = dpp_f<0x138>(d1);
        ks_level<0x111>(v0, v1, P1c, na1);
        ks_level<0x112>(v0, v1, P2c, na1);
        ks_level<0x114>(v0, v1, P4c, na1);
        ks_level<0x118>(v0, v1, P8c, na1);
        {   // row_bcast15 with per-lane power
            float t0 = dpp_f<0x142>(v0);
            float t1 = dpp_f<0x142>(v1);
            const bool g = (lane & 16) != 0;
            t0 = g ? t0 : 0.f;
            t1 = g ? t1 : 0.f;
            const float w = fmaf(na1, t0, t1);
            v0 = fmaf(Pme.x, w,  fmaf(Pme.y, t0, v0));
            v1 = fmaf(Pme.z, t0, fmaf(Pme.y, t1, v1));
        }
        {   // row_bcast31 with per-lane power
            float t0 = dpp_f<0x143>(v0);
            float t1 = dpp_f<0x143>(v1);
            const bool g = lane >= 32;
            t0 = g ? t0 : 0.f;
            t1 = g ? t1 : 0.f;
            const float w = fmaf(na1, t0, t1);
            v0 = fmaf(Qme.x, w,  fmaf(Qme.y, t0, v0));
            v1 = fmaf(Qme.z, t0, fmaf(Qme.y, t1, v1));
        }

        // reconstruct per-stream incoming states:
        // uS0 = v ; uS1 = A^8*uS0 + dS0 ; uS2 = A^16*uS0 + d01 ; uS3 = A^8*uS2 + dS2
        const float wr  = fmaf(na1, v0, v1);
        const float u1_0 = fmaf(al8, wr, fmaf(be8, v0, s1P.x));
        const float u1_1 = fmaf(ga8, v0, fmaf(be8, v1, s2P.x));
        const float u2_0 = fmaf(al16, wr, fmaf(be16, v0, d01_0));
        const float u2_1 = fmaf(ga16, v0, fmaf(be16, v1, d01_1));
        const float wr3  = fmaf(na1, u2_0, u2_1);
        const float u3_0 = fmaf(al8, wr3, fmaf(be8, u2_0, s1Q.x));
        const float u3_1 = fmaf(ga8, u2_0, fmaf(be8, u2_1, s2Q.x));

        // phase 2: packed homogeneous corrections (2 independent pk chains)
        f32x2 wP0 = {v0, u1_0}, wP1 = {v1, u1_1};
        f32x2 wQ0 = {u2_0, u3_0}, wQ1 = {u2_1, u3_1};
        #pragma unroll
        for (int t = 0; t < kSub; ++t) {
            const f32x2 cp = wP0;
            const f32x2 cq = wQ0;
            P[t] = pk_add(P[t], cp);
            Q[t] = pk_add(Q[t], cq);
            wP0 = pk_fma(na1p, cp, wP1);
            wQ0 = pk_fma(na1p, cq, wQ1);
            wP1 = pk_mul(na2p, cp);
            wQ1 = pk_mul(na2p, cq);
        }
    }

    // ---- unpack + store ----
    {
        float4* op = reinterpret_cast<float4*>(out + (size_t)ch * kFrame + lane * 32);
        op[0] = float4{P[0].x, P[1].x, P[2].x, P[3].x};
        op[1] = float4{P[4].x, P[5].x, P[6].x, P[7].x};
        op[2] = float4{P[0].y, P[1].y, P[2].y, P[3].y};
        op[3] = float4{P[4].y, P[5].y, P[6].y, P[7].y};
        op[4] = float4{Q[0].x, Q[1].x, Q[2].x, Q[3].x};
        op[5] = float4{Q[4].x, Q[5].x, Q[6].x, Q[7].x};
        op[6] = float4{Q[0].y, Q[1].y, Q[2].y, Q[3].y};
        op[7] = float4{Q[4].y, Q[5].y, Q[6].y, Q[7].y};
    }
}

} // namespace

extern "C" void kernel_launch(void* const* d_in, const int* in_sizes, int n_in,
                              void* d_out, int out_size, void* d_ws, size_t ws_size,
                              hipStream_t stream)
{
    (void)d_ws; (void)ws_size; (void)n_in; (void)in_sizes;
    const float* audio  = (const float*)d_in[0];
    const float* params = (const float*)d_in[1];
    float* outp = (float*)d_out;

    const int channels = out_size / kFrame;        // 2048
    hipLaunchKernelGGL(biquad_chain_kernel, dim3(channels), dim3(64), 0, stream,
                       audio, params, outp);
}

// Round 13
// 26.418 us; speedup vs baseline: 1.0495x; 1.0495x over previous
//
#include <hip/hip_runtime.h>
#include <math.h>

namespace {

constexpr int kNB    = 16;
constexpr int kFrame = 2048;
constexpr int kHalf  = 16;   // packed stream length (2 streams of 16 = 32 samples/lane)

typedef float f32x2 __attribute__((ext_vector_type(2)));

__device__ inline f32x2 pk_fma(f32x2 a, f32x2 b, f32x2 c) {
    f32x2 d;
    asm("v_pk_fma_f32 %0, %1, %2, %3" : "=v"(d) : "v"(a), "v"(b), "v"(c));
    return d;
}
__device__ inline f32x2 pk_mul(f32x2 a, f32x2 b) {
    f32x2 d;
    asm("v_pk_mul_f32 %0, %1, %2" : "=v"(d) : "v"(a), "v"(b));
    return d;
}
__device__ inline f32x2 pk_add(f32x2 a, f32x2 b) {
    f32x2 d;
    asm("v_pk_add_f32 %0, %1, %2" : "=v"(d) : "v"(a), "v"(b));
    return d;
}

// DPP move with bound_ctrl=1 (out-of-range -> 0)
template <int CTRL>
__device__ inline float dpp_f(float v) {
    return __int_as_float(
        __builtin_amdgcn_update_dpp(0, __float_as_int(v), CTRL, 0xF, 0xF, true));
}

// one uniform-matrix Kogge-Stone level via row_shr DPP (intra-row-16)
template <int CTRL>
__device__ inline void ks_level(float& v0, float& v1, const float4 M, const float na1) {
    const float t0 = dpp_f<CTRL>(v0);
    const float t1 = dpp_f<CTRL>(v1);
    const float w  = fmaf(na1, t0, t1);
    v0 = fmaf(M.x, w,  fmaf(M.y, t0, v0));
    v1 = fmaf(M.z, t0, fmaf(M.y, t1, v1));
}

// Block = 64 threads = 1 wave = 1 channel. Lane owns 32 consecutive samples
// (2 packed streams of 16). Scan across lanes is 100% DPP (no LDS round-trips).
__global__ __launch_bounds__(64)
void biquad_chain_kernel(const float* __restrict__ audio,
                         const float* __restrict__ params,
                         float* __restrict__ out)
{
    // sK[b][0] = (b0, b1, b2, na1); sK[b][1] = (na2, al16, be16, ga16)  [A^16]
    __shared__ float4 sK[kNB][2];
    // powT[b][i] = (al, be, ga, 0) for M^(i+1), M = A^32, i = 0..31 (col 33 pads)
    __shared__ float4 powT[kNB][33];

    const int lane = threadIdx.x & 63;
    const int ch   = blockIdx.x;      // 0..2047
    const int bb   = ch >> 7;
    const int ff   = ch & 127;

    const float* pb = params + (size_t)bb * (50 * 128) + ff;

    // ---- preamble: all 64 lanes; lane -> (band = lane&15, part = lane>>4) ----
    {
        const int band = lane & 15;
        const int part = lane >> 4;
        const double fn = (double)pb[(band * 3 + 0) * 128];
        const double gn = (double)pb[(band * 3 + 1) * 128];
        const double qn = (double)pb[(band * 3 + 2) * 128];
        const double PI   = 3.14159265358979323846;
        const double LN10 = 2.302585092994046;

        const bool isHP = (band == 0), isLP = (band == kNB - 1);
        const bool isShelf = (band == 1) || (band == kNB - 2);
        const double flo = isHP ? 2.995732273553991
                        : isLP ? 8.517193191416238
                        : isShelf ? 3.912023005428146
                        : 4.605170185988092;
        const double fsp = isHP ? 3.2188758248682006
                        : isLP ? 1.3862943611198906
                        : isShelf ? 5.768320995793772
                        : 5.0106352940962555;

        // uniform transcendental block
        const double Q  = exp(-0.6931471805599453 + qn * 3.4657359027997265);
        const double fc = exp(flo + fn * fsp);
        const double w0 = (2.0 * PI / 96000.0) * fc;
        const double sw = sin(w0);
        const double cw = cos(w0);
        const double al = sw / (2.0 * Q);
        const double gdb = (isHP || isLP) ? 0.0 : (-24.0 + gn * 48.0);
        const double A   = exp(gdb * (LN10 / 40.0));
        const double sA  = sqrt(A);
        const double ge = isHP ? (-60.0 + (double)pb[48 * 128] * 60.0) * (LN10 / 20.0)
                        : isLP ? (-60.0 + (double)pb[49 * 128] * 60.0) * (LN10 / 20.0)
                        : 0.0;
        const double gm = exp(ge);

        double b0, b1, b2, a0, a1, a2;
        if (isHP) {
            b0 = (1.0 + cw) * 0.5; b1 = -(1.0 + cw); b2 = (1.0 + cw) * 0.5;
            a0 = 1.0 + al; a1 = -2.0 * cw; a2 = 1.0 - al;
        } else if (isLP) {
            b0 = (1.0 - cw) * 0.5; b1 = 1.0 - cw; b2 = (1.0 - cw) * 0.5;
            a0 = 1.0 + al; a1 = -2.0 * cw; a2 = 1.0 - al;
        } else if (band == 1) {                // low shelf
            const double s2 = 2.0 * sA * al;
            b0 = A * ((A + 1.0) - (A - 1.0) * cw + s2);
            b1 = 2.0 * A * ((A - 1.0) - (A + 1.0) * cw);
            b2 = A * ((A + 1.0) - (A - 1.0) * cw - s2);
            a0 = (A + 1.0) + (A - 1.0) * cw + s2;
            a1 = -2.0 * ((A - 1.0) + (A + 1.0) * cw);
            a2 = (A + 1.0) + (A - 1.0) * cw - s2;
        } else if (band == kNB - 2) {          // high shelf
            const double s2 = 2.0 * sA * al;
            b0 = A * ((A + 1.0) + (A - 1.0) * cw + s2);
            b1 = -2.0 * A * ((A - 1.0) + (A + 1.0) * cw);
            b2 = A * ((A + 1.0) + (A - 1.0) * cw - s2);
            a0 = (A + 1.0) - (A - 1.0) * cw + s2;
            a1 = 2.0 * ((A - 1.0) - (A + 1.0) * cw);
            a2 = (A + 1.0) - (A - 1.0) * cw - s2;
        } else {                               // peaking
            b0 = 1.0 + al * A; b1 = -2.0 * cw; b2 = 1.0 - al * A;
            a0 = 1.0 + al / A; a1 = -2.0 * cw; a2 = 1.0 - al / A;
        }
        const double inv  = 1.0 / a0;
        const double binv = inv * gm;
        b0 *= binv; b1 *= binv; b2 *= binv; a1 *= inv; a2 *= inv;

        // CH doubling chain for A^(2^k), k=1..9; keep A^16, A^32 (=M), A^256, A^512
        double alc = 1.0, bec = 0.0;
        double al16 = 0, be16 = 0, al32 = 0, be32 = 0;
        double al256 = 0, be256 = 0, al512 = 0, be512 = 0;
        #pragma unroll
        for (int k = 1; k <= 9; ++k) {
            const double a_ = alc, b_ = bec;
            alc = a_ * (2.0 * b_ - a1 * a_);
            bec = b_ * b_ - a2 * (a_ * a_);
            if (k == 4) { al16 = alc; be16 = bec; }
            if (k == 5) { al32 = alc; be32 = bec; }
            if (k == 8) { al256 = alc; be256 = bec; }
            if (k == 9) { al512 = alc; be512 = bec; }
        }
        // compose (x*y) in the A-algebra: (alx A + bex I)(aly A + bey I)
        auto cmp = [&](double alx, double bex, double aly, double bey,
                       double& alo, double& beo) {
            const double p = alx * aly;
            alo = alx * bey + bex * aly - a1 * p;
            beo = bex * bey - a2 * p;
        };

        // part start: S = M^(8*part+1)
        double Sa, Sb;
        if (part == 0)      { Sa = al32; Sb = be32; }
        else if (part == 1) { cmp(al256, be256, al32, be32, Sa, Sb); }
        else if (part == 2) { cmp(al512, be512, al32, be32, Sa, Sb); }
        else { double ta, tb; cmp(al512, be512, al256, be256, ta, tb);
               cmp(ta, tb, al32, be32, Sa, Sb); }

        #pragma unroll
        for (int j = 0; j < 8; ++j) {
            powT[band][8 * part + j] =
                float4{(float)Sa, (float)Sb, (float)(-a2 * Sa), 0.f};
            double na, nb;
            cmp(Sa, Sb, al32, be32, na, nb);
            Sa = na; Sb = nb;
        }
        if (part == 0) {
            sK[band][0] = float4{(float)b0, (float)b1, (float)b2, (float)(-a1)};
            sK[band][1] = float4{(float)(-a2), (float)al16, (float)be16,
                                 (float)(-a2 * al16)};
        }
    }
    __syncthreads();

    // ---- load 32 samples, pack as 2 streams of 16: X[t] = (x[t], x[t+16]) ----
    f32x2 X[kHalf];
    {
        const float4* ap = reinterpret_cast<const float4*>(
            audio + (size_t)ch * kFrame + lane * 32);
        #pragma unroll
        for (int k = 0; k < 4; ++k) {
            const float4 va = ap[k];
            const float4 vb = ap[k + 4];
            X[4 * k + 0] = f32x2{va.x, vb.x};
            X[4 * k + 1] = f32x2{va.y, vb.y};
            X[4 * k + 2] = f32x2{va.z, vb.z};
            X[4 * k + 3] = f32x2{va.w, vb.w};
        }
    }

    // ---- cascade ----
    for (int band = 0; band < kNB; ++band) {
        const float4 k0 = sK[band][0];
        const float4 k1 = sK[band][1];
        const float4 P1 = powT[band][0];
        const float4 P2 = powT[band][1];
        const float4 P4 = powT[band][3];
        const float4 P8 = powT[band][7];
        const float4 Pme = powT[band][lane & 15];   // M^((lane&15)+1)
        const float4 Qme = powT[band][lane & 31];   // M^((lane&31)+1)

        const float b0 = k0.x, b1 = k0.y, b2 = k0.z, na1 = k0.w;
        const float na2 = k1.x, al16 = k1.y, be16 = k1.z, ga16 = k1.w;
        const f32x2 b0p  = {b0, b0},  b1p = {b1, b1}, b2p = {b2, b2};
        const f32x2 na1p = {na1, na1}, na2p = {na2, na2};

        // phase 1: two independent zero-state 16-sample streams (packed)
        f32x2 s1 = {0.f, 0.f}, s2 = {0.f, 0.f};
        #pragma unroll
        for (int t = 0; t < kHalf; ++t) {
            const f32x2 xv = X[t];
            const f32x2 y  = pk_fma(b0p, xv, s1);
            const f32x2 tm = pk_fma(b1p, xv, s2);
            s2 = pk_fma(na2p, y, pk_mul(b2p, xv));
            s1 = pk_fma(na1p, y, tm);
            X[t] = y;
        }

        // fold streams with A^16: d = A^16*dA + dB
        const float wf = fmaf(na1, s1.x, s2.x);
        const float d0 = fmaf(al16, wf, fmaf(be16, s1.x, s1.y));
        const float d1 = fmaf(ga16, s1.x, fmaf(be16, s2.x, s2.y));

        // ---- DS-free exclusive affine scan over 64 chunks, M = A^32 ----
        float v0 = dpp_f<0x138>(d0);     // wave_shr:1 (lane 0 -> 0)
        float v1 = dpp_f<0x138>(d1);
        ks_level<0x111>(v0, v1, P1, na1);
        ks_level<0x112>(v0, v1, P2, na1);
        ks_level<0x114>(v0, v1, P4, na1);
        ks_level<0x118>(v0, v1, P8, na1);
        {   // row_bcast15 with per-lane power
            float t0 = dpp_f<0x142>(v0);
            float t1 = dpp_f<0x142>(v1);
            const bool g = (lane & 16) != 0;
            t0 = g ? t0 : 0.f;
            t1 = g ? t1 : 0.f;
            const float w = fmaf(na1, t0, t1);
            v0 = fmaf(Pme.x, w,  fmaf(Pme.y, t0, v0));
            v1 = fmaf(Pme.z, t0, fmaf(Pme.y, t1, v1));
        }
        {   // row_bcast31 with per-lane power
            float t0 = dpp_f<0x143>(v0);
            float t1 = dpp_f<0x143>(v1);
            const bool g = lane >= 32;
            t0 = g ? t0 : 0.f;
            t1 = g ? t1 : 0.f;
            const float w = fmaf(na1, t0, t1);
            v0 = fmaf(Qme.x, w,  fmaf(Qme.y, t0, v0));
            v1 = fmaf(Qme.z, t0, fmaf(Qme.y, t1, v1));
        }

        // reconstruct stream-B incoming: uB = A^16*u + dA
        const float wr  = fmaf(na1, v0, v1);
        const float uB0 = fmaf(al16, wr, fmaf(be16, v0, s1.x));
        const float uB1 = fmaf(ga16, v0, fmaf(be16, v1, s2.x));

        // phase 2: packed homogeneous correction y(t) += [A^t * u]_0
        f32x2 w0 = {v0, uB0}, w1 = {v1, uB1};
        #pragma unroll
        for (int t = 0; t < kHalf; ++t) {
            const f32x2 c = w0;
            X[t] = pk_add(X[t], c);
            w0 = pk_fma(na1p, c, w1);
            w1 = pk_mul(na2p, c);
        }
    }

    // ---- unpack + store ----
    {
        float4* op = reinterpret_cast<float4*>(out + (size_t)ch * kFrame + lane * 32);
        #pragma unroll
        for (int k = 0; k < 4; ++k) {
            op[k]     = float4{X[4 * k + 0].x, X[4 * k + 1].x, X[4 * k + 2].x, X[4 * k + 3].x};
            op[k + 4] = float4{X[4 * k + 0].y, X[4 * k + 1].y, X[4 * k + 2].y, X[4 * k + 3].y};
        }
    }
}

} // namespace

extern "C" void kernel_launch(void* const* d_in, const int* in_sizes, int n_in,
                              void* d_out, int out_size, void* d_ws, size_t ws_size,
                              hipStream_t stream)
{
    (void)d_ws; (void)ws_size; (void)n_in; (void)in_sizes;
    const float* audio  = (const float*)d_in[0];
    const float* params = (const float*)d_in[1];
    float* outp = (float*)d_out;

    const int channels = out_size / kFrame;        // 2048
    hipLaunchKernelGGL(biquad_chain_kernel, dim3(channels), dim3(64), 0, stream,
                       audio, params, outp);
}